// Round 10
// baseline (194.954 us; speedup 1.0000x reference)
//
#include <hip/hip_runtime.h>
#include <math.h>

#define IS3 0.57735026918962576f   // 1/sqrt(3)
#define IS6 0.40824829046386302f   // 1/sqrt(6)

#define SHIFT 9                    // 512 nodes per bucket
#define BSZ   512
#define CAP   9216u                // slots per bucket (mean 8192, +11 sigma)
#define MQ    4096.0f              // message quantization scale (i16)
#define IMQ   (1.0f/4096.0f)

__device__ __forceinline__ float fastrcp(float x) { return __builtin_amdgcn_rcpf(x); }

// T(x) = tanh(w2 * tanh(w1*x)).
// Inner tanh: exp-based. Outer tanh: odd poly z - z^3/3 + 2z^5/15
// (|z| <= |w2| ~ 0.3 -> err <= ~4e-4, vs 0.1 budget).
__device__ __forceinline__ float Tnl(float x, float tw1, float w2) {
    float e = __expf(tw1 * x);
    float u = 1.0f - 2.0f * fastrcp(e + 1.0f);   // tanh(w1*x)
    float z = w2 * u;
    float z2 = z * z;
    float p = __builtin_fmaf(z2, 0.133333333f, -0.333333333f);
    return __builtin_fmaf(z * z2, p, z);
}

__device__ __forceinline__ int q16(float x) {
    int v = (int)rintf(x * MQ);
    v = v >  32767 ?  32767 : v;
    v = v < -32768 ? -32768 : v;
    return v;
}

// ---- K1: fused message compute + bucket routing (196 buckets of 512 nodes).
__global__ __launch_bounds__(1024) void route_kernel(
    const int* __restrict__ ei, const float* __restrict__ f,
    const float* __restrict__ d, const float* __restrict__ a,
    const float* __restrict__ w1p, const float* __restrict__ w2p,
    unsigned* __restrict__ tails,        // [nbuk*16] line-strided, pre-zeroed
    unsigned* __restrict__ qmeta,        // [nbuk*CAP]
    uint2* __restrict__ qmsg,            // [nbuk*CAP]
    int E, int nbuk)
{
    __shared__ unsigned hcnt[256];
    __shared__ unsigned hoff[256];
    int tid = threadIdx.x;
    if (tid < 256) hcnt[tid] = 0;
    __syncthreads();

    int e = blockIdx.x * 1024 + tid;
    bool valid = (e < E);
    int t = 0;
    unsigned b = 0, lrank = 0;
    if (valid) {
        t = ei[E + e];
        b = ((unsigned)t) >> SHIFT;
        lrank = atomicAdd(&hcnt[b], 1u);        // LDS int atomic (native)
    }
    __syncthreads();

    // reserve global chunk; result consumed after the heavy compute so the
    // returning atomic's latency hides under ~48 Tnl evaluations.
    unsigned basek = 0;
    if (tid < nbuk && hcnt[tid] != 0u)
        basek = atomicAdd(&tails[tid * 16], hcnt[tid]);

    unsigned dq = 0;
    uint2 pk = make_uint2(0u, 0u);
    if (valid) {
        int s = ei[e];
        float tw10 = 2.0f * w1p[0], tw11 = 2.0f * w1p[1];
        float w20 = w2p[0], w21 = w2p[1];

        const float4* f4 = (const float4*)f;
        float4 sA = f4[2*s], sB = f4[2*s+1];
        float4 tA = f4[2*t], tB = f4[2*t+1];
        float de = d[e];
        float4 av = ((const float4*)a)[e];
        float a0 = av.x, ax = av.y, ay = av.z, az = av.w;

        float sc[5] = { sA.x, sA.y, tA.x, tA.y, de };
        float vx[4] = { sA.z, sB.y, tA.z, tB.y };
        float vy[4] = { sA.w, sB.z, tA.w, tB.z };
        float vz[4] = { sB.x, sB.w, tB.x, tB.w };

        float mS = 0.f, mX = 0.f, mY = 0.f, mZ = 0.f;
        #pragma unroll
        for (int i = 0; i < 5; ++i) {
            mS += Tnl(sc[i] * a0, tw10, w20);
            mX += Tnl(sc[i] * ax * IS3, tw11, w21);
            mY += Tnl(sc[i] * ay * IS3, tw11, w21);
            mZ += Tnl(sc[i] * az * IS3, tw11, w21);
        }
        #pragma unroll
        for (int i = 0; i < 4; ++i) {
            float dva = vx[i]*ax + vy[i]*ay + vz[i]*az;
            mS += Tnl(dva * IS3, tw11, w21);
            mX += Tnl(vx[i] * a0 * IS3, tw10, w20);
            mY += Tnl(vy[i] * a0 * IS3, tw10, w20);
            mZ += Tnl(vz[i] * a0 * IS3, tw10, w20);
            float cx = vy[i]*az - vz[i]*ay;
            float cy = vz[i]*ax - vx[i]*az;
            float cz = vx[i]*ay - vy[i]*ax;
            mX += Tnl(cx * IS6, tw11, w21);
            mY += Tnl(cy * IS6, tw11, w21);
            mZ += Tnl(cz * IS6, tw11, w21);
        }

        unsigned dqi = (unsigned)(de * 2047.0f + 0.5f);
        dq = dqi > 2047u ? 2047u : dqi;
        int qS = q16(mS), qX = q16(mX), qY = q16(mY), qZ = q16(mZ);
        pk.x = ((unsigned)(unsigned short)qS) | (((unsigned)(unsigned short)qX) << 16);
        pk.y = ((unsigned)(unsigned short)qY) | (((unsigned)(unsigned short)qZ) << 16);
    }

    if (tid < nbuk) hoff[tid] = basek;   // s_waitcnt lands here, post-compute
    __syncthreads();

    if (valid) {
        unsigned pos = hoff[b] + lrank;
        if (pos < CAP) {                 // safety clamp; never hit
            size_t idx = (size_t)b * CAP + pos;
            qmeta[idx] = (((unsigned)(t & (BSZ - 1))) << 11) | dq;
            qmsg[idx]  = pk;
        }
    }
}

// ---- K2 (FUSED): one workgroup per bucket. Phase A: accumulate the whole
// bucket queue into LDS with 3 native int atomics per record. Phase B:
// thread=node decodes, computes invariants + MLP + gates + out — no partial
// array, no extra dispatch. MLP LDS reads are ds_read_b128 (W0 staged
// transposed+padded to 12; W1 rows / W2 rows read as float4).
__global__ __launch_bounds__(512) void fused_kernel(
    const unsigned* __restrict__ tails, const unsigned* __restrict__ qmeta,
    const uint2* __restrict__ qmsg, const float* __restrict__ f,
    const float* __restrict__ W0, const float* __restrict__ b0,
    const float* __restrict__ W1, const float* __restrict__ b1,
    const float* __restrict__ W2, const float* __restrict__ b2,
    float* __restrict__ out, int N)
{
    __shared__ unsigned long long accSX[BSZ];   // 4KB
    __shared__ unsigned long long accYZ[BSZ];   // 4KB
    __shared__ unsigned accM[BSZ];              // 2KB
    __shared__ float4 sW0t4[64*3];              // W0 transposed, rows of 12
    __shared__ float4 sW1v[64*8];
    __shared__ float4 sW2v[32];
    __shared__ float  sb0[64];
    __shared__ float4 sb1v[8];
    __shared__ float4 sb2v[1];

    int tid = threadIdx.x;
    int b = blockIdx.x;

    for (int i = tid; i < BSZ; i += 512) {
        accSX[i] = 0ull; accYZ[i] = 0ull; accM[i] = 0u;
    }
    float* w0t = (float*)sW0t4;
    for (int idx = tid; idx < 576; idx += 512) {   // coalesced W0 read
        int k = idx >> 6, i = idx & 63;
        w0t[i * 12 + k] = W0[idx];
    }
    if (tid < 192) {                               // zero the pad lanes
        int i = tid / 3, k = 9 + tid % 3;
        w0t[i * 12 + k] = 0.f;
    }
    { float* p = (float*)sW1v; for (int idx = tid; idx < 2048; idx += 512) p[idx] = W1[idx]; }
    { float* p = (float*)sW2v; if (tid < 128) p[tid] = W2[tid]; }
    if (tid < 64) sb0[tid] = b0[tid];
    { float* p = (float*)sb1v; if (tid < 32) p[tid] = b1[tid]; }
    { float* p = (float*)sb2v; if (tid < 4)  p[tid] = b2[tid]; }
    __syncthreads();

    unsigned tail = tails[b * 16];
    if (tail > CAP) tail = CAP;
    size_t base = (size_t)b * CAP;

    for (unsigned q = tid; q < tail; q += 512) {
        unsigned meta = qmeta[base + q];
        uint2 m = qmsg[base + q];
        int local = (int)(meta >> 11);
        int qS = (int)(short)(m.x & 0xFFFFu);
        int qX = (int)(short)(m.x >> 16);
        int qY = (int)(short)(m.y & 0xFFFFu);
        int qZ = (int)(short)(m.y >> 16);
        unsigned long long vSX =
            (((unsigned long long)(unsigned)qX) << 32) | (unsigned)(qS + 65536);
        unsigned long long vYZ =
            (((unsigned long long)(unsigned)qZ) << 32) | (unsigned)(qY + 65536);
        atomicAdd(&accSX[local], vSX);
        atomicAdd(&accYZ[local], vYZ);
        atomicAdd(&accM[local], (1u << 20) | (meta & 2047u));
    }
    __syncthreads();

    int n = b * BSZ + tid;
    if (n >= N) return;

    unsigned long long sx = accSX[tid], yz = accYZ[tid];
    unsigned m4 = accM[tid];
    int cnt = (int)(m4 >> 20);
    int S = (int)(unsigned)sx - (cnt << 16);
    int X = (int)(unsigned)(sx >> 32);
    int Y = (int)(unsigned)yz - (cnt << 16);
    int Z = (int)(unsigned)(yz >> 32);
    float aS = (float)S * IMQ, ax = (float)X * IMQ;
    float ay = (float)Y * IMQ, az = (float)Z * IMQ;
    float cf = (float)cnt;
    float dsum = (float)(m4 & 0xFFFFFu) * (1.0f / 2047.0f);

    float4 fA = ((const float4*)f)[2*n];
    float4 fB = ((const float4*)f)[2*n+1];

    float nrm1 = sqrtf(fA.z*fA.z + fA.w*fA.w + fB.x*fB.x);
    float nrm2 = sqrtf(fB.y*fB.y + fB.z*fB.z + fB.w*fB.w);
    float nv   = sqrtf(ax*ax + ay*ay + az*az);
    float avgd = dsum * fastrcp(cf + 1e-8f);
    float4 p0 = make_float4(fA.x, fA.y, nrm1, nrm2);
    float4 p1 = make_float4(aS, aS, nv, nv);
    float4 p2 = make_float4(avgd, 0.f, 0.f, 0.f);

    // layer1+layer2 interleaved, all LDS reads are b128
    float x1s[32];
    #pragma unroll
    for (int j = 0; j < 8; ++j) {
        float4 bv = sb1v[j];
        x1s[4*j+0] = bv.x; x1s[4*j+1] = bv.y; x1s[4*j+2] = bv.z; x1s[4*j+3] = bv.w;
    }
    #pragma unroll
    for (int i = 0; i < 64; ++i) {
        float4 r0 = sW0t4[i*3+0], r1 = sW0t4[i*3+1], r2 = sW0t4[i*3+2];
        float acc = sb0[i]
            + r0.x*p0.x + r0.y*p0.y + r0.z*p0.z + r0.w*p0.w
            + r1.x*p1.x + r1.y*p1.y + r1.z*p1.z + r1.w*p1.w
            + r2.x*p2.x;
        acc = fmaxf(acc, 0.f);
        #pragma unroll
        for (int j = 0; j < 8; ++j) {
            float4 wv = sW1v[i*8+j];
            x1s[4*j+0] += acc * wv.x;
            x1s[4*j+1] += acc * wv.y;
            x1s[4*j+2] += acc * wv.z;
            x1s[4*j+3] += acc * wv.w;
        }
    }
    #pragma unroll
    for (int j = 0; j < 32; ++j) x1s[j] = fmaxf(x1s[j], 0.f);

    float4 gb = sb2v[0];
    float g0 = gb.x, g1 = gb.y, g2 = gb.z, g3 = gb.w;
    #pragma unroll
    for (int i = 0; i < 32; ++i) {
        float4 wv = sW2v[i];
        g0 += x1s[i] * wv.x;
        g1 += x1s[i] * wv.y;
        g2 += x1s[i] * wv.z;
        g3 += x1s[i] * wv.w;
    }
    g0 = fastrcp(1.0f + __expf(-g0));
    g1 = fastrcp(1.0f + __expf(-g1));
    g2 = fastrcp(1.0f + __expf(-g2));
    g3 = fastrcp(1.0f + __expf(-g3));

    float* o = out + (size_t)8*n;
    o[0] = fA.x + g0*aS;
    o[1] = fA.y + g1*aS;
    o[2] = fA.z + g2*ax;
    o[3] = fA.w + g2*ay;
    o[4] = fB.x + g2*az;
    o[5] = fB.y + g3*ax;
    o[6] = fB.z + g3*ay;
    o[7] = fB.w + g3*az;
}

extern "C" void kernel_launch(void* const* d_in, const int* in_sizes, int n_in,
                              void* d_out, int out_size, void* d_ws, size_t ws_size,
                              hipStream_t stream) {
    const int*   ei = (const int*)d_in[0];
    const float* f  = (const float*)d_in[1];
    const float* d  = (const float*)d_in[2];
    const float* a  = (const float*)d_in[3];
    const float* w1 = (const float*)d_in[4];
    const float* w2 = (const float*)d_in[5];
    const float* W0 = (const float*)d_in[6];
    const float* b0 = (const float*)d_in[7];
    const float* W1 = (const float*)d_in[8];
    const float* b1 = (const float*)d_in[9];
    const float* W2 = (const float*)d_in[10];
    const float* b2 = (const float*)d_in[11];
    int E = in_sizes[0] / 2;
    int N = in_sizes[1] / 8;
    int nbuk = (N + BSZ - 1) >> SHIFT;          // 196 for N=100000

    // workspace layout (bytes), total ~21.7 MB:
    //   qmsg  : nbuk*CAP*8  @ 0
    //   qmeta : nbuk*CAP*4  @ qmsg_end
    //   tails : nbuk*16*4   @ qmeta_end (zeroed)
    char* w = (char*)d_ws;
    size_t qn = (size_t)nbuk * CAP;
    uint2*    qmsg  = (uint2*)w;
    unsigned* qmeta = (unsigned*)(w + qn * 8);
    unsigned* tails = (unsigned*)(w + qn * 12);

    hipMemsetAsync(tails, 0, (size_t)nbuk * 16 * sizeof(unsigned), stream);

    int EB = (E + 1023) / 1024;     // 1563
    route_kernel<<<dim3(EB), dim3(1024), 0, stream>>>(
        ei, f, d, a, w1, w2, tails, qmeta, qmsg, E, nbuk);
    fused_kernel<<<dim3(nbuk), dim3(512), 0, stream>>>(
        tails, qmeta, qmsg, f, W0, b0, W1, b1, W2, b2, (float*)d_out, N);
}

// Round 11
// 172.329 us; speedup vs baseline: 1.1313x; 1.1313x over previous
//
#include <hip/hip_runtime.h>
#include <math.h>

#define IS3 0.57735026918962576f   // 1/sqrt(3)
#define IS6 0.40824829046386302f   // 1/sqrt(6)

#define SHIFT 11                   // 2048 nodes per bucket
#define BSZ   2048
#define CAP   36864u               // slots per bucket (mean 32653, +23 sigma)
#define SEG   6                    // K2 workgroups per bucket
#define MQ    4096.0f              // message quantization scale (i16)
#define IMQ   (1.0f/4096.0f)

__device__ __forceinline__ float fastrcp(float x) { return __builtin_amdgcn_rcpf(x); }

// T(x) = tanh(w2 * tanh(w1*x)).
// Inner tanh: exp-based. Outer tanh: odd poly z - z^3/3 + 2z^5/15
// (|z| <= |w2| ~ 0.3 -> err <= ~4e-4, vs 0.1 budget).
__device__ __forceinline__ float Tnl(float x, float tw1, float w2) {
    float e = __expf(tw1 * x);
    float u = 1.0f - 2.0f * fastrcp(e + 1.0f);   // tanh(w1*x)
    float z = w2 * u;
    float z2 = z * z;
    float p = __builtin_fmaf(z2, 0.133333333f, -0.333333333f);
    return __builtin_fmaf(z * z2, p, z);
}

__device__ __forceinline__ int q16(float x) {
    int v = (int)rintf(x * MQ);
    v = v >  32767 ?  32767 : v;
    v = v < -32768 ? -32768 : v;
    return v;
}

// ---- K1: fused message compute + bucket routing (R9-proven geometry:
// 49 buckets of 2048 nodes, ~21-record chunks per (block,bucket)).
__global__ __launch_bounds__(1024) void route_kernel(
    const int* __restrict__ ei, const float* __restrict__ f,
    const float* __restrict__ d, const float* __restrict__ a,
    const float* __restrict__ w1p, const float* __restrict__ w2p,
    unsigned* __restrict__ tails,        // [nbuk*64] padded, pre-zeroed
    unsigned* __restrict__ qmeta,        // [nbuk*CAP]
    uint2* __restrict__ qmsg,            // [nbuk*CAP]
    int E, int nbuk)
{
    __shared__ unsigned hcnt[64];
    __shared__ unsigned hoff[64];
    int tid = threadIdx.x;
    if (tid < 64) hcnt[tid] = 0;
    __syncthreads();

    int e = blockIdx.x * 1024 + tid;
    bool valid = (e < E);
    int t = 0;
    unsigned b = 0, lrank = 0;
    if (valid) {
        t = ei[E + e];
        b = ((unsigned)t) >> SHIFT;
        lrank = atomicAdd(&hcnt[b], 1u);        // LDS int atomic (native)
    }
    __syncthreads();

    unsigned basek = 0;
    if (tid < nbuk && hcnt[tid] != 0u)
        basek = atomicAdd(&tails[tid * 64], hcnt[tid]);

    unsigned dq = 0;
    uint2 pk = make_uint2(0u, 0u);
    if (valid) {
        int s = ei[e];
        float tw10 = 2.0f * w1p[0], tw11 = 2.0f * w1p[1];
        float w20 = w2p[0], w21 = w2p[1];

        const float4* f4 = (const float4*)f;
        float4 sA = f4[2*s], sB = f4[2*s+1];
        float4 tA = f4[2*t], tB = f4[2*t+1];
        float de = d[e];
        float4 av = ((const float4*)a)[e];
        float a0 = av.x, ax = av.y, ay = av.z, az = av.w;

        float sc[5] = { sA.x, sA.y, tA.x, tA.y, de };
        float vx[4] = { sA.z, sB.y, tA.z, tB.y };
        float vy[4] = { sA.w, sB.z, tA.w, tB.z };
        float vz[4] = { sB.x, sB.w, tB.x, tB.w };

        float mS = 0.f, mX = 0.f, mY = 0.f, mZ = 0.f;
        #pragma unroll
        for (int i = 0; i < 5; ++i) {
            mS += Tnl(sc[i] * a0, tw10, w20);
            mX += Tnl(sc[i] * ax * IS3, tw11, w21);
            mY += Tnl(sc[i] * ay * IS3, tw11, w21);
            mZ += Tnl(sc[i] * az * IS3, tw11, w21);
        }
        #pragma unroll
        for (int i = 0; i < 4; ++i) {
            float dva = vx[i]*ax + vy[i]*ay + vz[i]*az;
            mS += Tnl(dva * IS3, tw11, w21);
            mX += Tnl(vx[i] * a0 * IS3, tw10, w20);
            mY += Tnl(vy[i] * a0 * IS3, tw10, w20);
            mZ += Tnl(vz[i] * a0 * IS3, tw10, w20);
            float cx = vy[i]*az - vz[i]*ay;
            float cy = vz[i]*ax - vx[i]*az;
            float cz = vx[i]*ay - vy[i]*ax;
            mX += Tnl(cx * IS6, tw11, w21);
            mY += Tnl(cy * IS6, tw11, w21);
            mZ += Tnl(cz * IS6, tw11, w21);
        }

        unsigned dqi = (unsigned)(de * 2047.0f + 0.5f);
        dq = dqi > 2047u ? 2047u : dqi;
        int qS = q16(mS), qX = q16(mX), qY = q16(mY), qZ = q16(mZ);
        pk.x = ((unsigned)(unsigned short)qS) | (((unsigned)(unsigned short)qX) << 16);
        pk.y = ((unsigned)(unsigned short)qY) | (((unsigned)(unsigned short)qZ) << 16);
    }

    if (tid < nbuk) hoff[tid] = basek;   // s_waitcnt lands here, post-compute
    __syncthreads();

    if (valid) {
        unsigned pos = hoff[b] + lrank;
        if (pos < CAP) {                 // safety clamp; never hit
            size_t idx = (size_t)b * CAP + pos;
            qmeta[idx] = (((unsigned)(t & (BSZ - 1))) << 11) | dq;
            qmsg[idx]  = pk;
        }
    }
}

// ---- K2: one workgroup per (bucket, segment). 3 native LDS atomics per
// record: two ds_add_u64 (bias-packed) + one u32. Flush = 5 SoA planes.
__global__ __launch_bounds__(1024) void bucket_kernel(
    const unsigned* __restrict__ tails, const unsigned* __restrict__ qmeta,
    const uint2* __restrict__ qmsg, unsigned* __restrict__ partial, int nbuk)
{
    __shared__ unsigned long long accSX[BSZ];   // 16KB
    __shared__ unsigned long long accYZ[BSZ];   // 16KB
    __shared__ unsigned accM[BSZ];              // 8KB
    int wg = blockIdx.x;
    int b = wg / SEG, sgi = wg % SEG;
    for (int i = threadIdx.x; i < BSZ; i += 1024) {
        accSX[i] = 0ull; accYZ[i] = 0ull; accM[i] = 0u;
    }
    __syncthreads();

    unsigned tail = tails[b * 64];
    if (tail > CAP) tail = CAP;
    unsigned lo = (unsigned)(((unsigned long long)tail * sgi) / SEG);
    unsigned hi = (unsigned)(((unsigned long long)tail * (sgi + 1)) / SEG);
    size_t base = (size_t)b * CAP;

    for (unsigned q = lo + threadIdx.x; q < hi; q += 1024) {
        unsigned meta = qmeta[base + q];
        uint2 m = qmsg[base + q];
        int local = (int)(meta >> 11);
        int qS = (int)(short)(m.x & 0xFFFFu);
        int qX = (int)(short)(m.x >> 16);
        int qY = (int)(short)(m.y & 0xFFFFu);
        int qZ = (int)(short)(m.y >> 16);
        unsigned long long vSX =
            (((unsigned long long)(unsigned)qX) << 32) | (unsigned)(qS + 65536);
        unsigned long long vYZ =
            (((unsigned long long)(unsigned)qZ) << 32) | (unsigned)(qY + 65536);
        atomicAdd(&accSX[local], vSX);
        atomicAdd(&accYZ[local], vYZ);
        atomicAdd(&accM[local], (1u << 20) | (meta & 2047u));
    }
    __syncthreads();

    unsigned* dst = partial + (size_t)wg * (BSZ * 5);
    for (int i = threadIdx.x; i < BSZ; i += 1024) {
        unsigned long long sx = accSX[i], yz = accYZ[i];
        dst[0*BSZ + i] = (unsigned)sx;
        dst[1*BSZ + i] = (unsigned)(sx >> 32);
        dst[2*BSZ + i] = (unsigned)yz;
        dst[3*BSZ + i] = (unsigned)(yz >> 32);
        dst[4*BSZ + i] = accM[i];
    }
}

// ---- K3: decode+sum SEG partials (exact int) + invariants + MLP + out.
// LDS-staged weights, all hot reads ds_read_b128 (W0 transposed+padded to
// 12 floats/row; W1 rows and W2 rows as float4) — R10-validated numerics.
__global__ __launch_bounds__(256) void mlp_kernel(
    const float* __restrict__ f, const unsigned* __restrict__ partial,
    const float* __restrict__ W0, const float* __restrict__ b0,
    const float* __restrict__ W1, const float* __restrict__ b1,
    const float* __restrict__ W2, const float* __restrict__ b2,
    float* __restrict__ out, int N)
{
    __shared__ float4 sW0t4[64*3];              // W0 transposed, rows of 12
    __shared__ float4 sW1v[64*8];
    __shared__ float4 sW2v[32];
    __shared__ float  sb0[64];
    __shared__ float4 sb1v[8];
    __shared__ float4 sb2v[1];

    int tid = threadIdx.x;
    float* w0t = (float*)sW0t4;
    for (int idx = tid; idx < 576; idx += 256) {   // coalesced W0 read
        int k = idx >> 6, i = idx & 63;
        w0t[i * 12 + k] = W0[idx];
    }
    if (tid < 192) {                               // zero the pad lanes
        int i = tid / 3, k = 9 + tid % 3;
        w0t[i * 12 + k] = 0.f;
    }
    { float* p = (float*)sW1v; for (int idx = tid; idx < 2048; idx += 256) p[idx] = W1[idx]; }
    { float* p = (float*)sW2v; if (tid < 128) p[tid] = W2[tid]; }
    if (tid < 64) sb0[tid] = b0[tid];
    { float* p = (float*)sb1v; if (tid < 32) p[tid] = b1[tid]; }
    { float* p = (float*)sb2v; if (tid < 4)  p[tid] = b2[tid]; }
    __syncthreads();

    int n = blockIdx.x * 256 + tid;
    if (n >= N) return;

    int b = n >> SHIFT;
    int local = n & (BSZ - 1);
    int S = 0, X = 0, Y = 0, Z = 0, cnt = 0, dqs = 0;
    #pragma unroll
    for (int s2 = 0; s2 < SEG; ++s2) {
        const unsigned* p = partial + ((size_t)(b * SEG + s2)) * (BSZ * 5);
        unsigned m4 = p[4*BSZ + local];
        int c = (int)(m4 >> 20);
        S += (int)p[0*BSZ + local] - (c << 16);
        X += (int)p[1*BSZ + local];
        Y += (int)p[2*BSZ + local] - (c << 16);
        Z += (int)p[3*BSZ + local];
        dqs += (int)(m4 & 0xFFFFFu);
        cnt += c;
    }
    float aS = (float)S * IMQ, ax = (float)X * IMQ;
    float ay = (float)Y * IMQ, az = (float)Z * IMQ;
    float cf = (float)cnt;
    float dsum = (float)dqs * (1.0f / 2047.0f);

    float4 fA = ((const float4*)f)[2*n];
    float4 fB = ((const float4*)f)[2*n+1];

    float nrm1 = sqrtf(fA.z*fA.z + fA.w*fA.w + fB.x*fB.x);
    float nrm2 = sqrtf(fB.y*fB.y + fB.z*fB.z + fB.w*fB.w);
    float nv   = sqrtf(ax*ax + ay*ay + az*az);
    float avgd = dsum * fastrcp(cf + 1e-8f);
    float4 p0 = make_float4(fA.x, fA.y, nrm1, nrm2);
    float4 p1 = make_float4(aS, aS, nv, nv);
    float4 p2 = make_float4(avgd, 0.f, 0.f, 0.f);

    // layer1+layer2 interleaved, all LDS reads are b128
    float x1s[32];
    #pragma unroll
    for (int j = 0; j < 8; ++j) {
        float4 bv = sb1v[j];
        x1s[4*j+0] = bv.x; x1s[4*j+1] = bv.y; x1s[4*j+2] = bv.z; x1s[4*j+3] = bv.w;
    }
    #pragma unroll
    for (int i = 0; i < 64; ++i) {
        float4 r0 = sW0t4[i*3+0], r1 = sW0t4[i*3+1], r2 = sW0t4[i*3+2];
        float acc = sb0[i]
            + r0.x*p0.x + r0.y*p0.y + r0.z*p0.z + r0.w*p0.w
            + r1.x*p1.x + r1.y*p1.y + r1.z*p1.z + r1.w*p1.w
            + r2.x*p2.x;
        acc = fmaxf(acc, 0.f);
        #pragma unroll
        for (int j = 0; j < 8; ++j) {
            float4 wv = sW1v[i*8+j];
            x1s[4*j+0] += acc * wv.x;
            x1s[4*j+1] += acc * wv.y;
            x1s[4*j+2] += acc * wv.z;
            x1s[4*j+3] += acc * wv.w;
        }
    }
    #pragma unroll
    for (int j = 0; j < 32; ++j) x1s[j] = fmaxf(x1s[j], 0.f);

    float4 gb = sb2v[0];
    float g0 = gb.x, g1 = gb.y, g2 = gb.z, g3 = gb.w;
    #pragma unroll
    for (int i = 0; i < 32; ++i) {
        float4 wv = sW2v[i];
        g0 += x1s[i] * wv.x;
        g1 += x1s[i] * wv.y;
        g2 += x1s[i] * wv.z;
        g3 += x1s[i] * wv.w;
    }
    g0 = fastrcp(1.0f + __expf(-g0));
    g1 = fastrcp(1.0f + __expf(-g1));
    g2 = fastrcp(1.0f + __expf(-g2));
    g3 = fastrcp(1.0f + __expf(-g3));

    float* o = out + (size_t)8*n;
    o[0] = fA.x + g0*aS;
    o[1] = fA.y + g1*aS;
    o[2] = fA.z + g2*ax;
    o[3] = fA.w + g2*ay;
    o[4] = fB.x + g2*az;
    o[5] = fB.y + g3*ax;
    o[6] = fB.z + g3*ay;
    o[7] = fB.w + g3*az;
}

extern "C" void kernel_launch(void* const* d_in, const int* in_sizes, int n_in,
                              void* d_out, int out_size, void* d_ws, size_t ws_size,
                              hipStream_t stream) {
    const int*   ei = (const int*)d_in[0];
    const float* f  = (const float*)d_in[1];
    const float* d  = (const float*)d_in[2];
    const float* a  = (const float*)d_in[3];
    const float* w1 = (const float*)d_in[4];
    const float* w2 = (const float*)d_in[5];
    const float* W0 = (const float*)d_in[6];
    const float* b0 = (const float*)d_in[7];
    const float* W1 = (const float*)d_in[8];
    const float* b1 = (const float*)d_in[9];
    const float* W2 = (const float*)d_in[10];
    const float* b2 = (const float*)d_in[11];
    int E = in_sizes[0] / 2;
    int N = in_sizes[1] / 8;
    int nbuk = (N + BSZ - 1) >> SHIFT;          // 49 for N=100000

    // workspace layout (bytes), total ~33.7 MB:
    //   qmsg    : nbuk*CAP*8       @ 0
    //   qmeta   : nbuk*CAP*4       @ qmsg_end
    //   partial : nbuk*SEG*BSZ*5*4 @ qmeta_end
    //   tails   : nbuk*64*4        @ partial_end (zeroed)
    char* w = (char*)d_ws;
    size_t qn = (size_t)nbuk * CAP;
    uint2*    qmsg    = (uint2*)w;
    unsigned* qmeta   = (unsigned*)(w + qn * 8);
    unsigned* partial = (unsigned*)(w + qn * 12);
    unsigned* tails   = (unsigned*)(w + qn * 12
                        + (size_t)nbuk * SEG * BSZ * 5 * 4);

    hipMemsetAsync(tails, 0, (size_t)nbuk * 64 * sizeof(unsigned), stream);

    int EB = (E + 1023) / 1024;     // 1563
    route_kernel <<<dim3(EB), dim3(1024), 0, stream>>>(
        ei, f, d, a, w1, w2, tails, qmeta, qmsg, E, nbuk);
    bucket_kernel<<<dim3(nbuk * SEG), dim3(1024), 0, stream>>>(
        tails, qmeta, qmsg, partial, nbuk);
    mlp_kernel   <<<dim3((N + 255) / 256), dim3(256), 0, stream>>>(
        f, partial, W0, b0, W1, b1, W2, b2, (float*)d_out, N);
}